// Round 1
// baseline (778.002 us; speedup 1.0000x reference)
//
#include <hip/hip_runtime.h>

#define GAP_OPEN_F (-4.0f)
#define GAP_EXT_F  (-1.0f)
#define NEG_BIG    (-1e30f)
#define LL 512
#define AA 511      // A = C = L-1
#define MM 511      // slots per diagonal
#define NDIAG 1021  // 2*A - 1

// One workgroup per batch. Thread j owns slot j of the anti-diagonal.
// DP state: 3 components (align, right, down) per slot, double-buffered in LDS.
// h0 overwrites the h2 buffer in place (thread j is the only reader of slot j
// in that buffer), so a single __syncthreads per diagonal suffices.
__global__ __launch_bounds__(512) void sw_dp_kernel(const float* __restrict__ pred,
                                                    const int* __restrict__ tgt,
                                                    float* __restrict__ partials) {
  __shared__ float PT[4 * LL];       // PT[p*512 + a] = pred[b][a][p]  (transposed: gather is conflict-free)
  __shared__ int   TG[LL];
  __shared__ float H[2][3][MM];      // [buf][state][slot]
  __shared__ float rm_s[8], rs_s[8];

  const int j = threadIdx.x;
  const int b = blockIdx.x;

  // ---- stage inputs ----
  {
    const float4 v = ((const float4*)pred)[b * LL + j];  // pred[b][j][0..3]
    PT[0 * LL + j] = v.x;
    PT[1 * LL + j] = v.y;
    PT[2 * LL + j] = v.z;
    PT[3 * LL + j] = v.w;
    TG[j] = tgt[b * LL + j];
  }
  if (j < MM) {
    for (int s = 0; s < 3; ++s) { H[0][s][j] = NEG_BIG; H[1][s][j] = NEG_BIG; }
  }
  __syncthreads();

  float m_acc = NEG_BIG;   // running max of (state + x2) over this thread's valid cells
  float s_acc = 0.0f;      // running sum of exp(v - m_acc)

  for (int d = 0; d < NDIAG; ++d) {
    const int cur = d & 1;   // h2 buffer index; h1 is cur^1; h0 written into cur
    if (j < MM) {
      const int par = d & 1;
      const int c = (d + 2 * j + par - (AA - 1)) / 2;  // exact: numerator always even
      const int a = d - c;
      const int valid = (a >= 0) & (a < AA) & (c >= 0) & (c < AA);

      float score = NEG_BIG;
      if (valid) score = PT[TG[c] * LL + a];

      // align = score + lse(h2[j].{A,R,D}, 0)
      const float g0 = H[cur][0][j], g1 = H[cur][1][j], g2 = H[cur][2][j];
      const float amx = fmaxf(fmaxf(g0, g1), fmaxf(g2, 0.0f));
      const float asum = __expf(g0 - amx) + __expf(g1 - amx) + __expf(g2 - amx) + __expf(-amx);
      const float align = score + amx + __logf(asum);

      // right = lse(left.A + GAP_OPEN, left.R + GAP_EXT);  left slot = j-1 (d even) or j (d odd)
      const int jl = par ? j : j - 1;
      float lA = NEG_BIG, lR = NEG_BIG;
      if (jl >= 0) { lA = H[cur ^ 1][0][jl]; lR = H[cur ^ 1][1][jl]; }
      const float r0 = lA + GAP_OPEN_F, r1 = lR + GAP_EXT_F;
      const float rmx = fmaxf(r0, r1);
      const float right = rmx + __logf(__expf(r0 - rmx) + __expf(r1 - rmx));

      // down = lse(up.A + GO, up.R + GO, up.D + GE);  up slot = j (d even) or j+1 (d odd)
      const int ju = par ? j + 1 : j;
      float uA = NEG_BIG, uR = NEG_BIG, uD = NEG_BIG;
      if (ju < MM) { uA = H[cur ^ 1][0][ju]; uR = H[cur ^ 1][1][ju]; uD = H[cur ^ 1][2][ju]; }
      const float d0 = uA + GAP_OPEN_F, d1 = uR + GAP_OPEN_F, d2 = uD + GAP_EXT_F;
      const float dmx = fmaxf(fmaxf(d0, d1), d2);
      const float down = dmx + __logf(__expf(d0 - dmx) + __expf(d1 - dmx) + __expf(d2 - dmx));

      // write h0 (in place over h2 buffer)
      H[cur][0][j] = align;
      H[cur][1][j] = right;
      H[cur][2][j] = down;

      // online logsumexp of (state + x[b][a+1][c+1]) over the 3 states
      if (valid) {
        const float x2 = PT[TG[c + 1] * LL + (a + 1)];
        const float vm = fmaxf(fmaxf(align, right), down);
        const float p  = __expf(align - vm) + __expf(right - vm) + __expf(down - vm);
        const float cm = vm + x2;
        const float nm = fmaxf(m_acc, cm);
        s_acc = s_acc * __expf(m_acc - nm) + p * __expf(cm - nm);
        m_acc = nm;
      }
    }
    __syncthreads();
  }

  // ---- block-level logsumexp merge of (m_acc, s_acc) ----
  for (int off = 32; off; off >>= 1) {
    const float om = __shfl_down(m_acc, off, 64);
    const float os = __shfl_down(s_acc, off, 64);
    const float nm = fmaxf(m_acc, om);
    s_acc = s_acc * __expf(m_acc - nm) + os * __expf(om - nm);
    m_acc = nm;
  }
  const int wave = j >> 6;
  if ((j & 63) == 0) { rm_s[wave] = m_acc; rs_s[wave] = s_acc; }
  __syncthreads();
  if (j == 0) {
    float M = rm_s[0], S = rs_s[0];
    for (int w = 1; w < 8; ++w) {
      const float om = rm_s[w], os = rs_s[w];
      const float nm = fmaxf(M, om);
      S = S * __expf(M - nm) + os * __expf(om - nm);
      M = nm;
    }
    partials[b] = M + __logf(S);   // final_b
  }
}

__global__ void sw_reduce_kernel(const float* __restrict__ partials, float* __restrict__ out) {
  const int t = threadIdx.x;
  float v = (t < 32) ? partials[t] : 0.0f;
  for (int off = 32; off; off >>= 1) v += __shfl_down(v, off, 64);
  if (t == 0) out[0] = -v * (1.0f / 32.0f);
}

extern "C" void kernel_launch(void* const* d_in, const int* in_sizes, int n_in,
                              void* d_out, int out_size, void* d_ws, size_t ws_size,
                              hipStream_t stream) {
  const float* pred = (const float*)d_in[0];   // (32, 512, 4) fp32
  const int*   tgt  = (const int*)d_in[1];     // (32, 512) int32
  float* partials = (float*)d_ws;              // 32 floats
  float* out = (float*)d_out;                  // scalar

  sw_dp_kernel<<<32, 512, 0, stream>>>(pred, tgt, partials);
  sw_reduce_kernel<<<1, 64, 0, stream>>>(partials, out);
}

// Round 2
// 385.976 us; speedup vs baseline: 2.0157x; 2.0157x over previous
//
#include <hip/hip_runtime.h>

#define EGO 0.018315638888734179f   // exp(-4)
#define EGE 0.36787944117144233f    // exp(-1)

// One wave (64 lanes) per batch. Slot j = lane + 64*s, s=0..7 (512 slots; slot 511 dead).
// Exp-domain DP: E = exp(h - Roff), Roff = Etot*ln2 maintained by power-of-2 rescales.
// align needs only the SUM of the 2-step-old states -> SE/SO regs (ungated s3).
// Contribution of valid cell (a,c): s3(a,c)*exp(x[a+1][c+1]) -> gated PE/PO regs,
// consumed 2 steps later when the same slot reads score(a+1,c+1).
__global__ __launch_bounds__(64) void sw_dp_kernel(const float* __restrict__ pred,
                                                   const int* __restrict__ tgt,
                                                   float* __restrict__ partials) {
  __shared__ float EPTp[2560];   // logical EPTp[256 + p*512 + a]; pads zeroed (a in [-256,766])
  __shared__ int   TGp[1024];    // logical TGp[256 + c]; pads zeroed (c in [-255,767])

  const int lane = (int)threadIdx.x;
  const int b = (int)blockIdx.x;

  // ---- stage exp(pred) (transposed) + targets + zero pads ----
  #pragma unroll
  for (int k = 0; k < 8; ++k) {
    const int i = lane + 64 * k;
    const float4 v = ((const float4*)pred)[b * 512 + i];
    EPTp[256 + 0 * 512 + i] = __expf(v.x);
    EPTp[256 + 1 * 512 + i] = __expf(v.y);
    EPTp[256 + 2 * 512 + i] = __expf(v.z);
    EPTp[256 + 3 * 512 + i] = __expf(v.w);
    TGp[256 + i] = tgt[b * 512 + i];
  }
  #pragma unroll
  for (int k = 0; k < 4; ++k) {
    EPTp[lane + 64 * k] = 0.0f;          // [0,256)
    EPTp[2304 + lane + 64 * k] = 0.0f;   // [2304,2560)
    TGp[lane + 64 * k] = 0;              // [0,256)
    TGp[768 + lane + 64 * k] = 0;        // [768,1024)
  }
  __syncthreads();

  // ---- per-slot constants & state ----
  int lo_[8], hi_[8], ai_[8], ci_[8];
  float A[8], R[8], D[8], SE[8], SO[8], PE[8], PO[8];
  #pragma unroll
  for (int s = 0; s < 8; ++s) {
    const int j = lane + 64 * s;
    const int lo1 = 509 - 2 * j, lo2 = 2 * j - 510;
    const int hi1 = 1530 - 2 * j, hi2 = 2 * j + 511;
    lo_[s] = lo1 > lo2 ? lo1 : lo2;
    hi_[s] = hi1 < hi2 ? hi1 : hi2;
    ai_[s] = 255 - j;        // a at pair p=0 (add 256+ inside index)
    ci_[s] = j + 1;          // 256 + c at pair p=0
    A[s] = R[s] = D[s] = 0.0f;
    SE[s] = SO[s] = PE[s] = PO[s] = 0.0f;
  }
  float ac0 = 0.0f, ac1 = 0.0f, ac2 = 0.0f, ac3 = 0.0f;
  float one = 1.0f;          // exp(0 - Roff) = 2^-Etot
  int Etot = 0;
  const int lane_m1 = (lane + 63) & 63;
  const int lane_p1 = (lane + 1) & 63;
  const bool is0 = (lane == 0);
  const bool is63 = (lane == 63);

  for (int p = 0; p < 511; ++p) {
    const int d = 2 * p;
    // ================= even step d: left = slot j-1, up = slot j =================
    float RC[8], rc[8];
    #pragma unroll
    for (int s = 0; s < 8; ++s) RC[s] = A[s] * EGO + R[s] * EGE;
    #pragma unroll
    for (int s = 0; s < 8; ++s) rc[s] = __shfl(RC[s], lane_m1, 64);
    #pragma unroll
    for (int s = 0; s < 8; ++s) {
      const bool val = (d >= lo_[s]) && (d <= hi_[s]);
      const int tg = TGp[ci_[s]];
      const float es = EPTp[256 + (tg << 9) + ai_[s]];
      float right;
      if (s == 0)      right = is0 ? 0.0f : rc[0];
      else             right = is0 ? rc[s - 1] : rc[s];
      if (s == 7)      right = is63 ? 0.0f : right;
      const float dn = (A[s] + R[s]) * EGO + D[s] * EGE;
      const float al = (val ? es : 0.0f) * (SE[s] + one);
      const float pa = PE[s] * es;
      if ((s & 3) == 0) ac0 += pa; else if ((s & 3) == 1) ac1 += pa;
      else if ((s & 3) == 2) ac2 += pa; else ac3 += pa;
      const float s3 = al + right + dn;
      SE[s] = s3;
      PE[s] = val ? s3 : 0.0f;
      A[s] = al; R[s] = right; D[s] = dn;
    }
    // ================= odd step d+1: left = slot j, up = slot j+1 =================
    float UC[8], uc[8];
    #pragma unroll
    for (int s = 0; s < 8; ++s) UC[s] = (A[s] + R[s]) * EGO + D[s] * EGE;
    #pragma unroll
    for (int s = 0; s < 8; ++s) uc[s] = __shfl(UC[s], lane_p1, 64);
    const int d1 = d + 1;
    #pragma unroll
    for (int s = 0; s < 8; ++s) {
      const bool val = (d1 >= lo_[s]) && (d1 <= hi_[s]);
      const int tg = TGp[ci_[s] + 1];
      const float es = EPTp[256 + (tg << 9) + ai_[s]];
      float dnv;
      if (s == 7)      dnv = is63 ? 0.0f : uc[7];
      else             dnv = is63 ? uc[s + 1] : uc[s];
      const float rt = A[s] * EGO + R[s] * EGE;
      const float al = (val ? es : 0.0f) * (SO[s] + one);
      const float pa = PO[s] * es;
      if ((s & 3) == 0) ac0 += pa; else if ((s & 3) == 1) ac1 += pa;
      else if ((s & 3) == 2) ac2 += pa; else ac3 += pa;
      const float s3 = al + rt + dnv;
      SO[s] = s3;
      PO[s] = val ? s3 : 0.0f;
      A[s] = al; R[s] = rt; D[s] = dnv;
      ai_[s] += 1; ci_[s] += 1;   // advance to next pair
    }
    // ================= periodic power-of-2 rescale =================
    if ((p & 15) == 15) {
      float m = 0.0f;
      #pragma unroll
      for (int s = 0; s < 8; ++s) m = fmaxf(m, fmaxf(fmaxf(A[s], R[s]), D[s]));
      #pragma unroll
      for (int off = 1; off < 64; off <<= 1) m = fmaxf(m, __shfl_xor(m, off, 64));
      if (m >= 2.0f) {
        const int ex = (int)(__float_as_uint(m) >> 23) & 0xff;   // biased exponent
        const float sc = __uint_as_float((unsigned)(253 - ex) << 23);  // 2^(126-ex)
        Etot += ex - 126;
        #pragma unroll
        for (int s = 0; s < 8; ++s) {
          A[s] *= sc; R[s] *= sc; D[s] *= sc;
          SE[s] *= sc; SO[s] *= sc; PE[s] *= sc; PO[s] *= sc;
        }
        ac0 *= sc; ac1 *= sc; ac2 *= sc; ac3 *= sc;
        one *= sc;
      }
    }
  }
  // ---- tail: phantom even step d=1022 consumes PE written at d=1020 ----
  #pragma unroll
  for (int s = 0; s < 8; ++s) {
    const int tg = TGp[ci_[s]];
    const float es = EPTp[256 + (tg << 9) + ai_[s]];
    const float pa = PE[s] * es;
    if ((s & 3) == 0) ac0 += pa; else if ((s & 3) == 1) ac1 += pa;
    else if ((s & 3) == 2) ac2 += pa; else ac3 += pa;
  }

  // ---- wave logsum: final_b = log(sum acc) + Etot*ln2 ----
  float atot = (ac0 + ac1) + (ac2 + ac3);
  #pragma unroll
  for (int off = 1; off < 64; off <<= 1) atot += __shfl_xor(atot, off, 64);
  if (lane == 0) partials[b] = __logf(atot) + (float)Etot * 0.69314718055994531f;
}

__global__ void sw_reduce_kernel(const float* __restrict__ partials, float* __restrict__ out) {
  const int t = (int)threadIdx.x;
  float v = (t < 32) ? partials[t] : 0.0f;
  for (int off = 32; off; off >>= 1) v += __shfl_down(v, off, 64);
  if (t == 0) out[0] = -v * (1.0f / 32.0f);
}

extern "C" void kernel_launch(void* const* d_in, const int* in_sizes, int n_in,
                              void* d_out, int out_size, void* d_ws, size_t ws_size,
                              hipStream_t stream) {
  const float* pred = (const float*)d_in[0];   // (32, 512, 4) fp32
  const int*   tgt  = (const int*)d_in[1];     // (32, 512) int32
  float* partials = (float*)d_ws;              // 32 floats
  float* out = (float*)d_out;                  // scalar

  sw_dp_kernel<<<32, 64, 0, stream>>>(pred, tgt, partials);
  sw_reduce_kernel<<<1, 64, 0, stream>>>(partials, out);
}

// Round 3
// 250.914 us; speedup vs baseline: 3.1007x; 1.5383x over previous
//
#include <hip/hip_runtime.h>

#define EGO 0.018315638888734179f   // exp(-4)
#define EGE 0.36787944117144233f    // exp(-1)

// One wave per batch. Slot j = 8*lane + s (s=0..7). Exp-domain DP.
// LDS layout: word index = ((idx&7)<<7) + (idx>>3)  -> lane stride 1 (conflict-free),
// and per-iteration addresses are base_reg + compile-time immediates (unroll 8).
__global__ __launch_bounds__(64) void sw_dp_kernel(const float* __restrict__ pred,
                                                   const int* __restrict__ tgt,
                                                   float* __restrict__ partials) {
  __shared__ float EPT[5120];   // 5 planes x 1024 words; plane = tg<<10 (plane 4 = zeros)
  __shared__ int   TG[1024];    // TG[phys(lc)] = tg<<10 for lc-256 in [0,512), else 4<<10

  const int lane = (int)threadIdx.x;
  const int b = (int)blockIdx.x;

  // ---------- staging ----------
  #pragma unroll
  for (int k = 0; k < 80; ++k) EPT[lane + 64 * k] = 0.0f;   // zero all planes
  #pragma unroll
  for (int k = 0; k < 16; ++k) {
    const int lc = lane + 64 * k;                            // 0..1023
    int vv = 4 << 10;
    if (lc >= 256 && lc < 768) vv = (tgt[b * 512 + (lc - 256)] << 10);
    TG[((lc & 7) << 7) + (lc >> 3)] = vv;
  }
  #pragma unroll
  for (int k = 0; k < 8; ++k) {
    const int a = lane + 64 * k;                             // 0..511 (la = 256+a)
    const float4 v = ((const float4*)pred)[b * 512 + a];
    const int base = ((a & 7) << 7) + 32 + (a >> 3);
    EPT[base]        = __expf(v.x);
    EPT[1024 + base] = __expf(v.y);
    EPT[2048 + base] = __expf(v.z);
    EPT[3072 + base] = __expf(v.w);
  }
  __syncthreads();

  // ---------- per-slot constants & state ----------
  int PE_[8], PO_[8];
  float A[8], R[8], D[8], SE[8], SO[8];
  #pragma unroll
  for (int s = 0; s < 8; ++s) {
    const int j = 8 * lane + s;
    const int pe1 = 255 + j, pe2 = 765 - j;
    PE_[s] = pe1 < pe2 ? pe1 : pe2;          // even-substep upper validity: p <= PE
    const int po2 = 764 - j;
    PO_[s] = pe1 < po2 ? pe1 : po2;          // odd-substep upper validity
    A[s] = R[s] = D[s] = 0.0f;
    SE[s] = SO[s] = 0.0f;
  }
  float ac0 = 0.0f, ac1 = 0.0f, ac2 = 0.0f, ac3 = 0.0f;
  float one = 1.0f;            // 2^-Etot
  int Etot = 0;
  const int lanem1 = (lane + 63) & 63;
  const int lanep1 = (lane + 1) & 63;
  const bool is0 = (lane == 0);
  const bool is63 = (lane == 63);

  // ---------- initial pipelined loads (p=0) ----------
  int tgO[8], tgE0[8];
  float esE[8], esO[8];
  #pragma unroll
  for (int s = 0; s < 8; ++s) {
    tgE0[s] = TG[lane + (((s + 1) & 7) << 7) + ((s + 1) >> 3)];
    tgO[s]  = TG[lane + (((s + 2) & 7) << 7) + ((s + 2) >> 3)];
  }
  #pragma unroll
  for (int s = 0; s < 8; ++s) {
    esE[s] = EPT[tgE0[s] + (63 - lane) + ((7 - s) << 7)];
    esO[s] = EPT[tgO[s]  + (63 - lane) + ((7 - s) << 7)];
  }

  int esWb = 63 - lane;   // es gather base (word), +1 per 8-iter block
  int tgWb = lane;        // tg gather base (word), +1 per 8-iter block
  float mcar = 0.0f;      // rescale partial max carried across blocks

  for (int b2 = 0; b2 < 64; ++b2) {
    #pragma unroll
    for (int t = 0; t < 8; ++t) {
      const int p = (b2 << 3) + t;
      const int pm1 = p - 1;

      // prefetch tg for next iteration's odd cell: TG[lc(p)+2]
      int tgN[8];
      #pragma unroll
      for (int s = 0; s < 8; ++s)
        tgN[s] = TG[tgWb + (((s + 3 + t) & 7) << 7) + ((s + 3 + t) >> 3)];

      // ---------- even substep (d = 2p): left = j-1, up = j ----------
      const float rc7 = A[7] * EGO + R[7] * EGE;
      float rcs = __shfl(rc7, lanem1, 64);
      float esEn[8];
      #pragma unroll
      for (int ss = 0; ss < 8; ++ss) {
        const int s = 7 - ss;   // descending
        float right;
        if (s == 0) right = is0 ? 0.0f : rcs;
        else        right = A[s - 1] * EGO + R[s - 1] * EGE;
        const float dn = (A[s] + R[s]) * EGO + D[s] * EGE;
        const bool val  = (p   <= PE_[s]);
        const bool valS = (pm1 <= PE_[s]);
        const float esg = val ? esE[s] : 0.0f;
        const float al  = esg * (SE[s] + one);
        const float pav = valS ? SE[s] : 0.0f;
        const float pa  = pav * esE[s];
        if ((s & 3) == 0) ac0 += pa; else if ((s & 3) == 1) ac1 += pa;
        else if ((s & 3) == 2) ac2 += pa; else ac3 += pa;
        const float s3 = al + right + dn;
        SE[s] = s3;
        A[s] = al; R[s] = right; D[s] = dn;
        // prefetch next even es (tg = tgO, la advances by 1)
        esEn[s] = EPT[tgO[s] + esWb + (((7 - s + t + 1) & 7) << 7) + ((7 - s + t + 1) >> 3)];
      }

      // ---------- odd substep (d = 2p+1): left = j, up = j+1 ----------
      const float uc0 = (A[0] + R[0]) * EGO + D[0] * EGE;
      float ucs = __shfl(uc0, lanep1, 64);
      #pragma unroll
      for (int s = 0; s < 8; ++s) {
        float dnv;
        if (s == 7) dnv = is63 ? 0.0f : ucs;
        else {
          dnv = (A[s + 1] + R[s + 1]) * EGO + D[s + 1] * EGE;
          if (s == 6) dnv = is63 ? 0.0f : dnv;   // slot 511 is phantom: must not leak
        }
        const float rt = A[s] * EGO + R[s] * EGE;
        const bool val  = (p   <= PO_[s]);
        const bool valS = (pm1 <= PO_[s]);
        const float esg = val ? esO[s] : 0.0f;
        const float al  = esg * (SO[s] + one);
        const float pav = valS ? SO[s] : 0.0f;
        const float pa  = pav * esO[s];
        if ((s & 3) == 0) ac0 += pa; else if ((s & 3) == 1) ac1 += pa;
        else if ((s & 3) == 2) ac2 += pa; else ac3 += pa;
        const float s3 = al + rt + dnv;
        SO[s] = s3;
        A[s] = al; R[s] = rt; D[s] = dnv;
      }

      // prefetch next odd es (tg = tgN, same la as next even)
      float esOn[8];
      #pragma unroll
      for (int s = 0; s < 8; ++s)
        esOn[s] = EPT[tgN[s] + esWb + (((7 - s + t + 1) & 7) << 7) + ((7 - s + t + 1) >> 3)];

      #pragma unroll
      for (int s = 0; s < 8; ++s) { tgO[s] = tgN[s]; esE[s] = esEn[s]; esO[s] = esOn[s]; }
    }
    ++esWb; ++tgWb;

    // ---------- rescale: measure at even blocks, finish+apply at odd blocks ----------
    if ((b2 & 1) == 0) {
      float mx = fmaxf(SE[0], SO[0]);
      #pragma unroll
      for (int s = 1; s < 8; ++s) mx = fmaxf(mx, fmaxf(SE[s], SO[s]));
      mx = fmaxf(mx, __shfl_xor(mx, 1, 64));
      mx = fmaxf(mx, __shfl_xor(mx, 2, 64));
      mx = fmaxf(mx, __shfl_xor(mx, 4, 64));
      mcar = mx;
    } else {
      float mx = mcar;
      mx = fmaxf(mx, __shfl_xor(mx, 8, 64));
      mx = fmaxf(mx, __shfl_xor(mx, 16, 64));
      mx = fmaxf(mx, __shfl_xor(mx, 32, 64));
      const int ex = (int)((__float_as_uint(mx) >> 23) & 0xff);
      const float sc = __uint_as_float((unsigned)(253 - ex) << 23);   // 2^(126-ex)
      Etot += ex - 126;
      #pragma unroll
      for (int s = 0; s < 8; ++s) {
        A[s] *= sc; R[s] *= sc; D[s] *= sc; SE[s] *= sc; SO[s] *= sc;
      }
      ac0 *= sc; ac1 *= sc; ac2 *= sc; ac3 *= sc;
      one *= sc;
    }
  }

  // ---------- wave logsum ----------
  float atot = (ac0 + ac1) + (ac2 + ac3);
  #pragma unroll
  for (int off = 1; off < 64; off <<= 1) atot += __shfl_xor(atot, off, 64);
  if (lane == 0) partials[b] = __logf(atot) + (float)Etot * 0.69314718055994531f;
}

__global__ void sw_reduce_kernel(const float* __restrict__ partials, float* __restrict__ out) {
  const int t = (int)threadIdx.x;
  float v = (t < 32) ? partials[t] : 0.0f;
  for (int off = 32; off; off >>= 1) v += __shfl_down(v, off, 64);
  if (t == 0) out[0] = -v * (1.0f / 32.0f);
}

extern "C" void kernel_launch(void* const* d_in, const int* in_sizes, int n_in,
                              void* d_out, int out_size, void* d_ws, size_t ws_size,
                              hipStream_t stream) {
  const float* pred = (const float*)d_in[0];   // (32, 512, 4) fp32
  const int*   tgt  = (const int*)d_in[1];     // (32, 512) int32
  float* partials = (float*)d_ws;              // 32 floats
  float* out = (float*)d_out;                  // scalar

  sw_dp_kernel<<<32, 64, 0, stream>>>(pred, tgt, partials);
  sw_reduce_kernel<<<1, 64, 0, stream>>>(partials, out);
}

// Round 4
// 236.867 us; speedup vs baseline: 3.2845x; 1.0593x over previous
//
#include <hip/hip_runtime.h>

#define EGO 0.018315638888734179f   // exp(-4)
#define EGE 0.36787944117144233f    // exp(-1)

// =====================================================================
// Fast path: precompute diag-major gathered exp(scores), then a lean DP.
// X[b][p][0][j] = exp(pred[b][a][tg[b][c]])   a=255-j+p, c=p+j-255 (0 if out of [0,511])
// X[b][p][1][j] = same with c+1.              p in [0,512)
// =====================================================================
__global__ __launch_bounds__(512) void sw_pre_kernel(const float* __restrict__ pred,
                                                     const int* __restrict__ tgt,
                                                     float* __restrict__ X) {
  const int j = (int)threadIdx.x;
  const int bp = (int)blockIdx.x;
  const int b = bp >> 9, p = bp & 511;
  const int a = 255 - j + p;
  const int c = p + j - 255;
  const bool av = (a >= 0) && (a < 512);
  float evn = 0.0f, odd = 0.0f;
  if (av && c >= 0 && c < 512)
    evn = __expf(pred[(((b << 9) + a) << 2) + tgt[(b << 9) + c]]);
  if (av && (c + 1) >= 0 && (c + 1) < 512)
    odd = __expf(pred[(((b << 9) + a) << 2) + tgt[(b << 9) + c + 1]]);
  float* base = X + (((size_t)((b << 9) + p)) << 10);
  base[j] = evn;
  base[512 + j] = odd;
}

// One wave per batch. Slot j = 8*lane + s. Exp-domain DP, all state in registers.
// Persistent per-slot state: U=A+R, D, RC=A*eGO+R*eGE (post-odd), SE/SO (s3 history),
// SEpa/SOpa (gated s3 for the pa term). es values stream from X, prefetched 4 deep.
__global__ __launch_bounds__(64) void sw_dp_fast(const float* __restrict__ X,
                                                 float* __restrict__ partials) {
  const int lane = (int)threadIdx.x;
  const int b = (int)blockIdx.x;
  const float* Xb = X + ((size_t)b << 19);   // b * 512 * 1024

  int PE_[8], PO_[8];
  float U[8], D[8], SE[8], SEpa[8], SO[8], SOpa[8], RC[8];
  float DC[8], RCe[8];
  #pragma unroll
  for (int s = 0; s < 8; ++s) {
    const int j = 8 * lane + s;
    const int e1 = 255 + j, e2 = 765 - j, o2 = 764 - j;
    PE_[s] = e1 < e2 ? e1 : e2;
    PO_[s] = e1 < o2 ? e1 : o2;
    U[s] = D[s] = SE[s] = SEpa[s] = SO[s] = SOpa[s] = RC[s] = 0.0f;
  }
  float acc[4] = {0.0f, 0.0f, 0.0f, 0.0f};
  float one = 1.0f;      // 2^-Etot
  int Etot = 0;
  const int lanem1 = (lane + 63) & 63;
  const int lanep1 = (lane + 1) & 63;
  const bool is0 = (lane == 0);
  const bool is63 = (lane == 63);

  float ev[4][8], od[4][8];

#define LOADP(par, p) do {                                                  \
    const float4* q_ = (const float4*)(Xb + ((size_t)(p) << 10));           \
    const float4 e0_ = q_[(lane << 1)], e1_ = q_[(lane << 1) + 1];          \
    const float4 o0_ = q_[128 + (lane << 1)], o1_ = q_[129 + (lane << 1)];  \
    ev[par][0] = e0_.x; ev[par][1] = e0_.y; ev[par][2] = e0_.z; ev[par][3] = e0_.w; \
    ev[par][4] = e1_.x; ev[par][5] = e1_.y; ev[par][6] = e1_.z; ev[par][7] = e1_.w; \
    od[par][0] = o0_.x; od[par][1] = o0_.y; od[par][2] = o0_.z; od[par][3] = o0_.w; \
    od[par][4] = o1_.x; od[par][5] = o1_.y; od[par][6] = o1_.z; od[par][7] = o1_.w; \
  } while (0)

#define EVENS(par, p) do {                                                  \
    float rcS = __shfl(RC[7], lanem1, 64);                                  \
    if (is0) rcS = 0.0f;                                                    \
    _Pragma("unroll")                                                       \
    for (int s = 0; s < 8; ++s) {                                           \
      const float right = (s == 0) ? rcS : RC[s - 1];                       \
      const float dn = U[s] * EGO + D[s] * EGE;                             \
      const bool v = ((p) <= PE_[s]);                                       \
      const float raw = ev[par][s];                                         \
      acc[s & 3] += SEpa[s] * raw;                                          \
      const float esg = v ? raw : 0.0f;                                     \
      const float al = esg * (SE[s] + one);                                 \
      const float Un = al + right;                                          \
      const float s3 = Un + dn;                                             \
      SE[s] = s3; SEpa[s] = v ? s3 : 0.0f;                                  \
      U[s] = Un; D[s] = dn;                                                 \
      DC[s] = Un * EGO + dn * EGE;                                          \
      RCe[s] = al * EGO + right * EGE;                                      \
    }                                                                       \
    if (is63) DC[7] = 0.0f;  /* slot 511 is phantom */                      \
  } while (0)

#define ODDS(par, p) do {                                                   \
    float dcS = __shfl(DC[0], lanep1, 64);                                  \
    if (is63) dcS = 0.0f;                                                   \
    _Pragma("unroll")                                                       \
    for (int s = 0; s < 8; ++s) {                                           \
      const float dnv = (s == 7) ? dcS : DC[s + 1];                         \
      const float right = RCe[s];                                           \
      const bool v = ((p) <= PO_[s]);                                       \
      const float raw = od[par][s];                                         \
      acc[s & 3] += SOpa[s] * raw;                                          \
      const float esg = v ? raw : 0.0f;                                     \
      const float al = esg * (SO[s] + one);                                 \
      const float Un = al + right;                                          \
      const float s3 = Un + dnv;                                            \
      SO[s] = s3; SOpa[s] = v ? s3 : 0.0f;                                  \
      U[s] = Un; D[s] = dnv;                                                \
      RC[s] = al * EGO + right * EGE;                                       \
    }                                                                       \
  } while (0)

  // initial prefetch: raw(0..3)
  LOADP(0, 0); LOADP(1, 1); LOADP(2, 2); LOADP(3, 3);

  for (int qq = 0; qq < 127; ++qq) {
    const int p0 = qq << 2;
    EVENS(0, p0);     ODDS(0, p0);     LOADP(0, p0 + 4);
    EVENS(1, p0 + 1); ODDS(1, p0 + 1); LOADP(1, p0 + 5);
    EVENS(2, p0 + 2); ODDS(2, p0 + 2); LOADP(2, p0 + 6);
    EVENS(3, p0 + 3); ODDS(3, p0 + 3); LOADP(3, p0 + 7);
    if ((qq & 3) == 3) {
      float mx = fmaxf(SE[0], SO[0]);
      #pragma unroll
      for (int s = 1; s < 8; ++s) mx = fmaxf(mx, fmaxf(SE[s], SO[s]));
      #pragma unroll
      for (int off = 1; off < 64; off <<= 1) mx = fmaxf(mx, __shfl_xor(mx, off, 64));
      const int ex = (int)((__float_as_uint(mx) >> 23) & 0xff);
      const float sc = __uint_as_float((unsigned)(253 - ex) << 23);  // 2^(126-ex)
      Etot += ex - 126;
      #pragma unroll
      for (int s = 0; s < 8; ++s) {
        U[s] *= sc; D[s] *= sc; RC[s] *= sc;
        SE[s] *= sc; SEpa[s] *= sc; SO[s] *= sc; SOpa[s] *= sc;
      }
      acc[0] *= sc; acc[1] *= sc; acc[2] *= sc; acc[3] *= sc;
      one *= sc;
    }
  }
  // tail: p = 508, 509, 510 (no further loads)
  EVENS(0, 508); ODDS(0, 508);
  EVENS(1, 509); ODDS(1, 509);
  EVENS(2, 510); ODDS(2, 510);
  // epilogue p = 511: pa-only, consumes raw(511) in buffer 3
  #pragma unroll
  for (int s = 0; s < 8; ++s) {
    acc[s & 3] += SEpa[s] * ev[3][s];
    acc[s & 3] += SOpa[s] * od[3][s];
  }

  float atot = (acc[0] + acc[1]) + (acc[2] + acc[3]);
  #pragma unroll
  for (int off = 1; off < 64; off <<= 1) atot += __shfl_xor(atot, off, 64);
  if (lane == 0) partials[b] = __logf(atot) + (float)Etot * 0.69314718055994531f;

#undef LOADP
#undef EVENS
#undef ODDS
}

// =====================================================================
// Fallback (R3, validated absmax 0.0): used when ws_size is too small.
// =====================================================================
__global__ __launch_bounds__(64) void sw_dp_kernel(const float* __restrict__ pred,
                                                   const int* __restrict__ tgt,
                                                   float* __restrict__ partials) {
  __shared__ float EPT[5120];
  __shared__ int   TG[1024];

  const int lane = (int)threadIdx.x;
  const int b = (int)blockIdx.x;

  #pragma unroll
  for (int k = 0; k < 80; ++k) EPT[lane + 64 * k] = 0.0f;
  #pragma unroll
  for (int k = 0; k < 16; ++k) {
    const int lc = lane + 64 * k;
    int vv = 4 << 10;
    if (lc >= 256 && lc < 768) vv = (tgt[b * 512 + (lc - 256)] << 10);
    TG[((lc & 7) << 7) + (lc >> 3)] = vv;
  }
  #pragma unroll
  for (int k = 0; k < 8; ++k) {
    const int a = lane + 64 * k;
    const float4 v = ((const float4*)pred)[b * 512 + a];
    const int base = ((a & 7) << 7) + 32 + (a >> 3);
    EPT[base]        = __expf(v.x);
    EPT[1024 + base] = __expf(v.y);
    EPT[2048 + base] = __expf(v.z);
    EPT[3072 + base] = __expf(v.w);
  }
  __syncthreads();

  int PE_[8], PO_[8];
  float A[8], R[8], D[8], SE[8], SO[8];
  #pragma unroll
  for (int s = 0; s < 8; ++s) {
    const int j = 8 * lane + s;
    const int pe1 = 255 + j, pe2 = 765 - j;
    PE_[s] = pe1 < pe2 ? pe1 : pe2;
    const int po2 = 764 - j;
    PO_[s] = pe1 < po2 ? pe1 : po2;
    A[s] = R[s] = D[s] = 0.0f;
    SE[s] = SO[s] = 0.0f;
  }
  float ac0 = 0.0f, ac1 = 0.0f, ac2 = 0.0f, ac3 = 0.0f;
  float one = 1.0f;
  int Etot = 0;
  const int lanem1 = (lane + 63) & 63;
  const int lanep1 = (lane + 1) & 63;
  const bool is0 = (lane == 0);
  const bool is63 = (lane == 63);

  int tgO[8], tgE0[8];
  float esE[8], esO[8];
  #pragma unroll
  for (int s = 0; s < 8; ++s) {
    tgE0[s] = TG[lane + (((s + 1) & 7) << 7) + ((s + 1) >> 3)];
    tgO[s]  = TG[lane + (((s + 2) & 7) << 7) + ((s + 2) >> 3)];
  }
  #pragma unroll
  for (int s = 0; s < 8; ++s) {
    esE[s] = EPT[tgE0[s] + (63 - lane) + ((7 - s) << 7)];
    esO[s] = EPT[tgO[s]  + (63 - lane) + ((7 - s) << 7)];
  }

  int esWb = 63 - lane;
  int tgWb = lane;
  float mcar = 0.0f;

  for (int b2 = 0; b2 < 64; ++b2) {
    #pragma unroll
    for (int t = 0; t < 8; ++t) {
      const int p = (b2 << 3) + t;
      const int pm1 = p - 1;

      int tgN[8];
      #pragma unroll
      for (int s = 0; s < 8; ++s)
        tgN[s] = TG[tgWb + (((s + 3 + t) & 7) << 7) + ((s + 3 + t) >> 3)];

      const float rc7 = A[7] * EGO + R[7] * EGE;
      float rcs = __shfl(rc7, lanem1, 64);
      float esEn[8];
      #pragma unroll
      for (int ss = 0; ss < 8; ++ss) {
        const int s = 7 - ss;
        float right;
        if (s == 0) right = is0 ? 0.0f : rcs;
        else        right = A[s - 1] * EGO + R[s - 1] * EGE;
        const float dn = (A[s] + R[s]) * EGO + D[s] * EGE;
        const bool val  = (p   <= PE_[s]);
        const bool valS = (pm1 <= PE_[s]);
        const float esg = val ? esE[s] : 0.0f;
        const float al  = esg * (SE[s] + one);
        const float pav = valS ? SE[s] : 0.0f;
        const float pa  = pav * esE[s];
        if ((s & 3) == 0) ac0 += pa; else if ((s & 3) == 1) ac1 += pa;
        else if ((s & 3) == 2) ac2 += pa; else ac3 += pa;
        const float s3 = al + right + dn;
        SE[s] = s3;
        A[s] = al; R[s] = right; D[s] = dn;
        esEn[s] = EPT[tgO[s] + esWb + (((7 - s + t + 1) & 7) << 7) + ((7 - s + t + 1) >> 3)];
      }

      const float uc0 = (A[0] + R[0]) * EGO + D[0] * EGE;
      float ucs = __shfl(uc0, lanep1, 64);
      #pragma unroll
      for (int s = 0; s < 8; ++s) {
        float dnv;
        if (s == 7) dnv = is63 ? 0.0f : ucs;
        else {
          dnv = (A[s + 1] + R[s + 1]) * EGO + D[s + 1] * EGE;
          if (s == 6) dnv = is63 ? 0.0f : dnv;
        }
        const float rt = A[s] * EGO + R[s] * EGE;
        const bool val  = (p   <= PO_[s]);
        const bool valS = (pm1 <= PO_[s]);
        const float esg = val ? esO[s] : 0.0f;
        const float al  = esg * (SO[s] + one);
        const float pav = valS ? SO[s] : 0.0f;
        const float pa  = pav * esO[s];
        if ((s & 3) == 0) ac0 += pa; else if ((s & 3) == 1) ac1 += pa;
        else if ((s & 3) == 2) ac2 += pa; else ac3 += pa;
        const float s3 = al + rt + dnv;
        SO[s] = s3;
        A[s] = al; R[s] = rt; D[s] = dnv;
      }

      float esOn[8];
      #pragma unroll
      for (int s = 0; s < 8; ++s)
        esOn[s] = EPT[tgN[s] + esWb + (((7 - s + t + 1) & 7) << 7) + ((7 - s + t + 1) >> 3)];

      #pragma unroll
      for (int s = 0; s < 8; ++s) { tgO[s] = tgN[s]; esE[s] = esEn[s]; esO[s] = esOn[s]; }
    }
    ++esWb; ++tgWb;

    if ((b2 & 1) == 0) {
      float mx = fmaxf(SE[0], SO[0]);
      #pragma unroll
      for (int s = 1; s < 8; ++s) mx = fmaxf(mx, fmaxf(SE[s], SO[s]));
      mx = fmaxf(mx, __shfl_xor(mx, 1, 64));
      mx = fmaxf(mx, __shfl_xor(mx, 2, 64));
      mx = fmaxf(mx, __shfl_xor(mx, 4, 64));
      mcar = mx;
    } else {
      float mx = mcar;
      mx = fmaxf(mx, __shfl_xor(mx, 8, 64));
      mx = fmaxf(mx, __shfl_xor(mx, 16, 64));
      mx = fmaxf(mx, __shfl_xor(mx, 32, 64));
      const int ex = (int)((__float_as_uint(mx) >> 23) & 0xff);
      const float sc = __uint_as_float((unsigned)(253 - ex) << 23);
      Etot += ex - 126;
      #pragma unroll
      for (int s = 0; s < 8; ++s) {
        A[s] *= sc; R[s] *= sc; D[s] *= sc; SE[s] *= sc; SO[s] *= sc;
      }
      ac0 *= sc; ac1 *= sc; ac2 *= sc; ac3 *= sc;
      one *= sc;
    }
  }

  float atot = (ac0 + ac1) + (ac2 + ac3);
  #pragma unroll
  for (int off = 1; off < 64; off <<= 1) atot += __shfl_xor(atot, off, 64);
  if (lane == 0) partials[b] = __logf(atot) + (float)Etot * 0.69314718055994531f;
}

__global__ void sw_reduce_kernel(const float* __restrict__ partials, float* __restrict__ out) {
  const int t = (int)threadIdx.x;
  float v = (t < 32) ? partials[t] : 0.0f;
  for (int off = 32; off; off >>= 1) v += __shfl_down(v, off, 64);
  if (t == 0) out[0] = -v * (1.0f / 32.0f);
}

extern "C" void kernel_launch(void* const* d_in, const int* in_sizes, int n_in,
                              void* d_out, int out_size, void* d_ws, size_t ws_size,
                              hipStream_t stream) {
  const float* pred = (const float*)d_in[0];   // (32, 512, 4) fp32
  const int*   tgt  = (const int*)d_in[1];     // (32, 512) int32
  float* partials = (float*)d_ws;              // 32 floats at offset 0
  float* out = (float*)d_out;                  // scalar

  // X needs 32*512*1024 floats = 64 MiB at offset 1024.
  if (ws_size >= (size_t)67109888ULL) {
    float* X = (float*)((char*)d_ws + 1024);
    sw_pre_kernel<<<16384, 512, 0, stream>>>(pred, tgt, X);
    sw_dp_fast<<<32, 64, 0, stream>>>(X, partials);
  } else {
    sw_dp_kernel<<<32, 64, 0, stream>>>(pred, tgt, partials);
  }
  sw_reduce_kernel<<<1, 64, 0, stream>>>(partials, out);
}